// Round 5
// baseline (63.745 us; speedup 1.0000x reference)
//
#include <hip/hip_runtime.h>

// steps = 65536, channels = 6, state = [pos(6), vel(6)]
// Closed form of the scan:
//   S_t = sum_{i<=t} a_i        (per channel)
//   W_t = sum_{i<=t} i * a_i    (per channel)
//   vel[t] = v0 + dt*S_t
//   pos[t] = p0 + dt*(t+1)*v0 + dt^2*((t+0.5)*S_t - W_t)
// Output layout: states [65536,12] flat, then actions [65536,6] flat.
//
// SINGLE regular launch (graph-capturable). Unconditional harness costs in
// the timed region: 256 MiB d_ws poison ~40.4us + out poison + gaps ~10us.
//
// Barrier history: R2 fences+acquire-spin = 68us (per-poll L2 invalidates).
// R3 relaxed ticket = 15.2us. R4 distributed flags = 13.1us. The ~10us floor
// shared by R3/R4 is NOT the barrier: it's phase 2 reading g_bsum via
// agent-scope ATOMIC loads — uncoalesced, uncached 8B transactions at the
// coherence point: 256 blk x 6 waves x ~256 lanes x 2 = ~390K serialized ops.
// This version: phase 2 uses PLAIN CACHED double2 loads. Correctness:
//   - release side (verified in R3/R4): __syncthreads drains vmcnt(0) before
//     s_barrier, so each block's g_bsum atomic stores are acked at the
//     coherence point (memory-side LLC, always coherent) BEFORE its flag RMW.
//   - acquire side: after wave 0 observes all 256 flags, it executes ONE
//     __builtin_amdgcn_fence(ACQUIRE, "agent") -> one buffer_inv dropping
//     this CU's L1 + XCD L2 lines (nothing dirty pre-barrier, so ~free).
//     Plain loads after the following __syncthreads refetch from the LLC.
//     This is one invalidate per block, NOT per poll (R2's mistake).
// Flags: per-block 64B-padded monotonic epochs, relaxed RMW arrival, wave-0
// sweep (lane L owns L, L+64, L+128, L+192). No reset -> graph-replay-safe,
// re-poison-safe (static __device__, never poisoned; zero-init = launch 0).
// Liveness: 256 blocks, 18 KiB LDS, ~32 VGPR -> all blocks co-resident.

#define STEPS   65536
#define NCH     6
#define STATE   12
#define NB      256
#define CHUNK   (STEPS / NB)        // 256 steps per block
#define BLK     (NCH * 64)          // 384 threads = 6 waves; wave w <-> channel w
#define ACT_OFF (STEPS * STATE)     // float offset of actions region in out

__device__ double             g_bsum[NB * NCH * 2];   // static scratch (NOT d_ws)
__device__ unsigned long long g_flag[NB * 8];         // per-block epoch flags, 64B apart

__global__ __launch_bounds__(BLK) void k_fused(const float4* __restrict__ act4,
                                               const float* __restrict__ x,
                                               float* __restrict__ out) {
    __shared__ float sIn[CHUNK * NCH];      // 6 KiB  — action chunk, persists across barrier
    __shared__ float sOut[CHUNK * STATE];   // 12 KiB — state chunk for coalesced writeout
    __shared__ unsigned long long sEpoch;
    const int b = blockIdx.x, tid = threadIdx.x;

    // Coalesced stage-in (passthrough store deferred to after the barrier so
    // the pre-barrier vmcnt drain only covers the tiny g_bsum atomics).
    float4 v = act4[b * (CHUNK * NCH / 4) + tid];
    ((float4*)sIn)[tid] = v;
    __syncthreads();

    const int c = tid >> 6, lane = tid & 63;

    // ---- Phase 1: per-(block,channel) partial sums ----
    {
        double sA = 0.0, sW = 0.0;
#pragma unroll
        for (int k = 0; k < 4; ++k) {
            const int   tl = k * 64 + lane;
            const float a  = sIn[tl * NCH + c];
            sA += (double)a;
            sW += (double)(b * CHUNK + tl) * (double)a;
        }
#pragma unroll
        for (int off = 32; off > 0; off >>= 1) {
            sA += __shfl_down(sA, off, 64);
            sW += __shfl_down(sW, off, 64);
        }
        if (lane == 0) {
            __hip_atomic_store(&g_bsum[(b * NCH + c) * 2 + 0], sA,
                               __ATOMIC_RELAXED, __HIP_MEMORY_SCOPE_AGENT);
            __hip_atomic_store(&g_bsum[(b * NCH + c) * 2 + 1], sW,
                               __ATOMIC_RELAXED, __HIP_MEMORY_SCOPE_AGENT);
        }
    }

    // ---- Distributed flag barrier (relaxed polls, ONE acquire fence) ----
    __syncthreads();            // drains vmcnt(0): g_bsum stores acked at LLC
    if (tid == 0) {
        unsigned long long old = __hip_atomic_fetch_add(&g_flag[b * 8], 1ULL,
                                                        __ATOMIC_RELAXED,
                                                        __HIP_MEMORY_SCOPE_AGENT);
        sEpoch = old + 1ULL;    // launch-uniform epoch
    }
    __syncthreads();
    const unsigned long long e = sEpoch;
    if (tid < 64) {
        unsigned pend = 0xFu;   // lane owns flags lane, lane+64, lane+128, lane+192
        for (;;) {
#pragma unroll
            for (int j = 0; j < 4; ++j) {
                if (pend & (1u << j)) {
                    unsigned long long f =
                        __hip_atomic_load(&g_flag[(lane + 64 * j) * 8],
                                          __ATOMIC_RELAXED,
                                          __HIP_MEMORY_SCOPE_AGENT);
                    if (f >= e) pend &= ~(1u << j);
                }
            }
            if (__all(pend == 0u)) break;
            __builtin_amdgcn_s_sleep(1);
        }
        // One cache invalidate per block: subsequent PLAIN loads see the
        // coherence point. Nothing dirty in L1/L2 pre-barrier -> ~free.
        __builtin_amdgcn_fence(__ATOMIC_ACQUIRE, "agent");
    }
    __syncthreads();            // release all 6 waves; full compiler barrier

    // Actions passthrough (independent of barrier; overlaps phase 2).
    ((float4*)(out + ACT_OFF))[b * (CHUNK * NCH / 4) + tid] = v;

    // ---- Phase 2: cross-block exclusive prefix, PLAIN cached loads ----
    double offA, offW;
    {
        const double2* bs2 = (const double2*)g_bsum;   // [block][ch] = {sA, sW}
        double vA = 0.0, vW = 0.0;
#pragma unroll
        for (int k = 0; k < 4; ++k) {
            const int idx = k * 64 + lane;
            if (idx < b) {
                const double2 p = bs2[idx * NCH + c];  // 16B vector load, L1/L2 cached
                vA += p.x;
                vW += p.y;
            }
        }
#pragma unroll
        for (int off = 32; off > 0; off >>= 1) {
            vA += __shfl_down(vA, off, 64);
            vW += __shfl_down(vW, off, 64);
        }
        offA = __shfl(vA, 0, 64);
        offW = __shfl(vW, 0, 64);
    }

    const double dt  = (double)0.1f;   // match float32(0.1) bit pattern
    const double dt2 = dt * dt;
    const double p0  = (double)x[c];
    const double v0  = (double)x[NCH + c];

    double accA = offA, accW = offW;   // running totals before current 64-tile
#pragma unroll
    for (int k = 0; k < 4; ++k) {
        const int   tl = k * 64 + lane;
        const int   t  = b * CHUNK + tl;
        const float a  = sIn[tl * NCH + c];
        double iA = (double)a;
        double iW = (double)t * (double)a;
        // Inclusive 64-lane scan (lane <-> t, stride 1).
#pragma unroll
        for (int off = 1; off < 64; off <<= 1) {
            const double uA = __shfl_up(iA, off, 64);
            const double uW = __shfl_up(iW, off, 64);
            if (lane >= off) { iA += uA; iW += uW; }
        }
        const double runA = accA + iA;
        const double runW = accW + iW;
        const double vel = v0 + dt * runA;
        const double pos = p0 + dt * (double)(t + 1) * v0
                         + dt2 * (((double)t + 0.5) * runA - runW);
        sOut[tl * STATE + c]       = (float)pos;
        sOut[tl * STATE + NCH + c] = (float)vel;
        accA += __shfl(iA, 63, 64);    // add tile total
        accW += __shfl(iW, 63, 64);
    }
    __syncthreads();

    // Coalesced writeout of the 256x12 state chunk: 768 float4, 2/thread.
    const float4* so4 = (const float4*)sOut;
    float4*       o4  = (float4*)out;
    o4[b * (CHUNK * STATE / 4) + tid]       = so4[tid];
    o4[b * (CHUNK * STATE / 4) + BLK + tid] = so4[BLK + tid];
}

extern "C" void kernel_launch(void* const* d_in, const int* in_sizes, int n_in,
                              void* d_out, int out_size, void* d_ws, size_t ws_size,
                              hipStream_t stream) {
    const float*  x    = (const float*)d_in[0];   // 12 floats: pos(6), vel(6)
    const float4* act4 = (const float4*)d_in[1];  // [65536, 6] as float4
    float*        out  = (float*)d_out;           // states(786432) + actions(393216)

    hipLaunchKernelGGL(k_fused, dim3(NB), dim3(BLK), 0, stream,
                       act4, x, out);
}

// Round 6
// 63.247 us; speedup vs baseline: 1.0079x; 1.0079x over previous
//
#include <hip/hip_runtime.h>

// steps = 65536, channels = 6, state = [pos(6), vel(6)]
// Closed form of the scan:
//   S_t = sum_{i<=t} a_i        (per channel)
//   W_t = sum_{i<=t} i * a_i    (per channel)
//   vel[t] = v0 + dt*S_t
//   pos[t] = p0 + dt*(t+1)*v0 + dt^2*((t+0.5)*S_t - W_t)
// Output layout: states [65536,12] flat, then actions [65536,6] flat.
//
// SINGLE regular launch (graph-capturable). Unconditional harness cost:
// 256 MiB d_ws poison ~40.4us + out poison + ~9us dispatch gaps (calibrated
// vs R2 where k_fused=68us pinned fills+gaps at 50.5us).
//
// Barrier history: R2 fences+acquire spin 68us; R3 relaxed single ticket
// 15.2us; R4 distributed flags 13.1us; R5 plain phase-2 loads + one acquire
// fence 13.2us (no change -> phase-2 load mechanism exonerated). Remaining
// theory: dead time in the wait window + detection tail. This version:
//   - arrival: PLAIN relaxed store of epoch e (own flag pre-read at kernel
//     start, latency hidden under stage-in). Ordering kept from R3-R5's
//     verified mechanism: __syncthreads drains vmcnt(0), so g_bsum stores
//     are acked at the coherence point before the flag store issues.
//   - detection: MASTER-BROADCAST. Only block 0 wave 0 sweeps the 256
//     per-block flags, then stores one g_go word; all other blocks poll
//     g_go with one wave (read-only line, no RMW contention).
//   - overlap: actions passthrough store + the register-resident local
//     inclusive scans (the dependent 6-step double-shuffle chains) run
//     BETWEEN arrival and poll, hiding under the barrier wait. Post-barrier
//     work is only: prefix reduce + 4 combines + sOut + writeout.
// Epoch invariant: all flags equal at every launch boundary (each block
// stores e exactly once per launch; monotonic; zero-init = launch 0), so
// e = own_flag + 1 is launch-uniform. Graph-replay-safe, re-poison-safe
// (static __device__, never poisoned). Liveness: master only requires all
// blocks to REACH their unconditional flag store; 256 blocks, 18.5 KiB LDS,
// <=96 VGPR -> all 256 blocks co-resident on 256 CUs.

#define STEPS   65536
#define NCH     6
#define STATE   12
#define NB      256
#define CHUNK   (STEPS / NB)        // 256 steps per block
#define BLK     (NCH * 64)          // 384 threads = 6 waves; wave w <-> channel w
#define ACT_OFF (STEPS * STATE)     // float offset of actions region in out

__device__ double             g_bsum[NB * NCH * 2];   // static scratch (NOT d_ws)
__device__ unsigned long long g_flag[NB * 8];         // per-block epoch flags, 64B apart
__device__ unsigned long long g_go;                   // master's broadcast word

__global__ __launch_bounds__(BLK) void k_fused(const float4* __restrict__ act4,
                                               const float* __restrict__ x,
                                               float* __restrict__ out) {
    __shared__ float sIn[CHUNK * NCH];      // 6 KiB  — action chunk
    __shared__ float sOut[CHUNK * STATE];   // 12 KiB — state chunk for coalesced writeout
    __shared__ unsigned long long sEpoch;
    const int b = blockIdx.x, tid = threadIdx.x;
    const int c = tid >> 6, lane = tid & 63;

    // Early issue: stage-in load, x[] loads, own-flag epoch read (all latency
    // hidden under each other and phase 1).
    float4 v = act4[b * (CHUNK * NCH / 4) + tid];
    const double p0 = (double)x[c];
    const double v0 = (double)x[NCH + c];
    unsigned long long myflag = 0ULL;
    if (tid == 0)
        myflag = __hip_atomic_load(&g_flag[b * 8], __ATOMIC_RELAXED,
                                   __HIP_MEMORY_SCOPE_AGENT);
    ((float4*)sIn)[tid] = v;
    __syncthreads();                                    // #1

    // ---- Phase 1: per-(block,channel) partial sums (fast path to arrival) ----
    {
        double sA = 0.0, sW = 0.0;
#pragma unroll
        for (int k = 0; k < 4; ++k) {
            const int   tl = k * 64 + lane;
            const float a  = sIn[tl * NCH + c];
            sA += (double)a;
            sW += (double)(b * CHUNK + tl) * (double)a;
        }
#pragma unroll
        for (int off = 32; off > 0; off >>= 1) {
            sA += __shfl_down(sA, off, 64);
            sW += __shfl_down(sW, off, 64);
        }
        if (lane == 0) {
            __hip_atomic_store(&g_bsum[(b * NCH + c) * 2 + 0], sA,
                               __ATOMIC_RELAXED, __HIP_MEMORY_SCOPE_AGENT);
            __hip_atomic_store(&g_bsum[(b * NCH + c) * 2 + 1], sW,
                               __ATOMIC_RELAXED, __HIP_MEMORY_SCOPE_AGENT);
        }
    }
    if (tid == 0) sEpoch = myflag + 1ULL;   // launch-uniform epoch
    __syncthreads();                        // #2: drains bsum stores, publishes sEpoch
    const unsigned long long e = sEpoch;
    if (tid == 0)                           // arrival: plain store, fire-and-forget
        __hip_atomic_store(&g_flag[b * 8], e,
                           __ATOMIC_RELAXED, __HIP_MEMORY_SCOPE_AGENT);

    // ---- Overlap window (hides under other blocks' arrivals) ----
    // Actions passthrough store: barrier-independent.
    ((float4*)(out + ACT_OFF))[b * (CHUNK * NCH / 4) + tid] = v;

    // Master sweep: block 0 wave 0 only; then broadcast via g_go.
    if (b == 0 && tid < 64) {
        unsigned pend = 0xFu;   // lane owns flags lane, lane+64, lane+128, lane+192
        for (;;) {
#pragma unroll
            for (int j = 0; j < 4; ++j) {
                if (pend & (1u << j)) {
                    unsigned long long f =
                        __hip_atomic_load(&g_flag[(lane + 64 * j) * 8],
                                          __ATOMIC_RELAXED,
                                          __HIP_MEMORY_SCOPE_AGENT);
                    if (f >= e) pend &= ~(1u << j);
                }
            }
            if (__all(pend == 0u)) break;
            __builtin_amdgcn_s_sleep(1);
        }
        if (lane == 0)
            __hip_atomic_store(&g_go, e,
                               __ATOMIC_RELAXED, __HIP_MEMORY_SCOPE_AGENT);
    }

    // Local inclusive scans (register-resident, dependent shuffle chains):
    // runs during the barrier wait.
    double iA[4], iW[4], tTotA[4], tTotW[4];
#pragma unroll
    for (int k = 0; k < 4; ++k) {
        const int   tl = k * 64 + lane;
        const int   t  = b * CHUNK + tl;
        const float a  = sIn[tl * NCH + c];
        double a_ = (double)a;
        double w_ = (double)t * (double)a;
#pragma unroll
        for (int off = 1; off < 64; off <<= 1) {
            const double uA = __shfl_up(a_, off, 64);
            const double uW = __shfl_up(w_, off, 64);
            if (lane >= off) { a_ += uA; w_ += uW; }
        }
        iA[k] = a_;  iW[k] = w_;
        tTotA[k] = __shfl(a_, 63, 64);
        tTotW[k] = __shfl(w_, 63, 64);
    }

    // ---- Wait for broadcast (one wave polls one read-only line) ----
    if (tid < 64) {
        while (__hip_atomic_load(&g_go, __ATOMIC_RELAXED,
                                 __HIP_MEMORY_SCOPE_AGENT) < e) {
            __builtin_amdgcn_s_sleep(1);
        }
        // One invalidate per block so subsequent PLAIN loads see the LLC.
        __builtin_amdgcn_fence(__ATOMIC_ACQUIRE, "agent");
    }
    __syncthreads();                        // #3

    // ---- Phase 2: cross-block exclusive prefix (plain cached loads) ----
    double offA, offW;
    {
        const double2* bs2 = (const double2*)g_bsum;   // [block][ch] = {sA, sW}
        double vA = 0.0, vW = 0.0;
#pragma unroll
        for (int k = 0; k < 4; ++k) {
            const int idx = k * 64 + lane;
            if (idx < b) {
                const double2 p = bs2[idx * NCH + c];
                vA += p.x;
                vW += p.y;
            }
        }
#pragma unroll
        for (int off = 32; off > 0; off >>= 1) {
            vA += __shfl_down(vA, off, 64);
            vW += __shfl_down(vW, off, 64);
        }
        offA = __shfl(vA, 0, 64);
        offW = __shfl(vW, 0, 64);
    }

    // ---- Combine (cheap: scans already done) + sOut + writeout ----
    const double dt  = (double)0.1f;   // match float32(0.1) bit pattern
    const double dt2 = dt * dt;
    double accA = offA, accW = offW;
#pragma unroll
    for (int k = 0; k < 4; ++k) {
        const int tl = k * 64 + lane;
        const int t  = b * CHUNK + tl;
        const double runA = accA + iA[k];
        const double runW = accW + iW[k];
        const double vel = v0 + dt * runA;
        const double pos = p0 + dt * (double)(t + 1) * v0
                         + dt2 * (((double)t + 0.5) * runA - runW);
        sOut[tl * STATE + c]       = (float)pos;
        sOut[tl * STATE + NCH + c] = (float)vel;
        accA += tTotA[k];
        accW += tTotW[k];
    }
    __syncthreads();                        // #4

    // Coalesced writeout of the 256x12 state chunk: 768 float4, 2/thread.
    const float4* so4 = (const float4*)sOut;
    float4*       o4  = (float4*)out;
    o4[b * (CHUNK * STATE / 4) + tid]       = so4[tid];
    o4[b * (CHUNK * STATE / 4) + BLK + tid] = so4[BLK + tid];
}

extern "C" void kernel_launch(void* const* d_in, const int* in_sizes, int n_in,
                              void* d_out, int out_size, void* d_ws, size_t ws_size,
                              hipStream_t stream) {
    const float*  x    = (const float*)d_in[0];   // 12 floats: pos(6), vel(6)
    const float4* act4 = (const float4*)d_in[1];  // [65536, 6] as float4
    float*        out  = (float*)d_out;           // states(786432) + actions(393216)

    hipLaunchKernelGGL(k_fused, dim3(NB), dim3(BLK), 0, stream,
                       act4, x, out);
}

// Round 7
// 62.453 us; speedup vs baseline: 1.0207x; 1.0127x over previous
//
#include <hip/hip_runtime.h>

// steps = 65536, channels = 6, state = [pos(6), vel(6)]
// Closed form of the scan:
//   S_t = sum_{i<=t} a_i        (per channel)
//   W_t = sum_{i<=t} i * a_i    (per channel)
//   vel[t] = v0 + dt*S_t
//   pos[t] = p0 + dt*(t+1)*v0 + dt^2*((t+0.5)*S_t - W_t)
// Output layout: states [65536,12] flat, then actions [65536,6] flat.
//
// STRUCTURE VERDICT (R0-R6 measured): two plain kernels with a HW dispatch
// boundary as the grid sync = 62.4us (best). Fused single kernel with an
// in-kernel barrier converged at 63.2us across 4 barrier designs (ticket,
// distributed flags, master-broadcast, full overlap): an in-kernel grid sync
// costs ~7us — MORE than the ~3.4us kernel boundary it replaces. The timed
// region is dominated by unconditional harness work: 256 MiB d_ws poison
// fill ~41us @83% HBM peak + ~3.1us/dispatch gaps. This file is the R0
// structure + two safe micro-opts in k_final:
//   1. cross-block prefix loads hoisted ABOVE the LDS staging, so their
//      cold-LLC latency hides under stage-in + local scans;
//   2. prefix reads as double2 vector loads (same values, same add order).
// k_partial is byte-identical to the R0 version. bsum lives in d_ws (it is
// fully rewritten by k_partial before k_final reads it every launch, so the
// unconditional poison is harmless).

#define STEPS   65536
#define NCH     6
#define STATE   12
#define NB      256
#define CHUNK   (STEPS / NB)        // 256 steps per block
#define BLK     (NCH * 64)          // 384 threads = 6 waves; wave w <-> channel w
#define ACT_OFF (STEPS * STATE)     // float offset of actions region in out

__global__ __launch_bounds__(BLK) void k_partial(const float4* __restrict__ act4,
                                                 float4* __restrict__ outact4,
                                                 double* __restrict__ bsum) {
    __shared__ float sIn[CHUNK * NCH];          // 6 KiB
    const int b = blockIdx.x, tid = threadIdx.x;

    // Coalesced stage-in + actions passthrough (coalesced float4 store).
    float4 v = act4[b * (CHUNK * NCH / 4) + tid];
    outact4[b * (CHUNK * NCH / 4) + tid] = v;
    ((float4*)sIn)[tid] = v;
    __syncthreads();

    const int c = tid >> 6, lane = tid & 63;
    double sA = 0.0, sW = 0.0;
#pragma unroll
    for (int k = 0; k < 4; ++k) {
        const int   tl = k * 64 + lane;
        const float a  = sIn[tl * NCH + c];
        sA += (double)a;
        sW += (double)(b * CHUNK + tl) * (double)a;
    }
#pragma unroll
    for (int off = 32; off > 0; off >>= 1) {
        sA += __shfl_down(sA, off, 64);
        sW += __shfl_down(sW, off, 64);
    }
    if (lane == 0) {
        bsum[(b * NCH + c) * 2 + 0] = sA;
        bsum[(b * NCH + c) * 2 + 1] = sW;
    }
}

__global__ __launch_bounds__(BLK) void k_final(const float4* __restrict__ act4,
                                               const float* __restrict__ x,
                                               const double* __restrict__ bsum,
                                               float4* __restrict__ out4) {
    __shared__ float sIn[CHUNK * NCH];          // 6 KiB
    __shared__ float sOut[CHUNK * STATE];       // 12 KiB
    const int b = blockIdx.x, tid = threadIdx.x;
    const int c = tid >> 6, lane = tid & 63;

    // Issue the stage-in load first (HBM/LLC latency in flight)...
    float4 v = act4[b * (CHUNK * NCH / 4) + tid];

    // ...then issue the cross-block prefix loads (cold-LLC, 4 double2/lane)
    // so they resolve while we stage + scan. Same values/add-order as R0.
    double vA = 0.0, vW = 0.0;
    {
        const double2* bs2 = (const double2*)bsum;   // [block][ch] = {sA, sW}
#pragma unroll
        for (int k = 0; k < 4; ++k) {
            const int idx = k * 64 + lane;
            if (idx < b) {
                const double2 p = bs2[idx * NCH + c];
                vA += p.x;
                vW += p.y;
            }
        }
    }

    ((float4*)sIn)[tid] = v;
    __syncthreads();

    const double dt  = (double)0.1f;   // match float32(0.1) bit pattern
    const double dt2 = dt * dt;
    const double p0  = (double)x[c];
    const double v0  = (double)x[NCH + c];

    // Local inclusive 64-lane scans (lane <-> t, stride 1), overlapping the
    // in-flight prefix loads.
    double iA[4], iW[4], tTotA[4], tTotW[4];
#pragma unroll
    for (int k = 0; k < 4; ++k) {
        const int   tl = k * 64 + lane;
        const int   t  = b * CHUNK + tl;
        const float a  = sIn[tl * NCH + c];
        double a_ = (double)a;
        double w_ = (double)t * (double)a;
#pragma unroll
        for (int off = 1; off < 64; off <<= 1) {
            const double uA = __shfl_up(a_, off, 64);
            const double uW = __shfl_up(w_, off, 64);
            if (lane >= off) { a_ += uA; w_ += uW; }
        }
        iA[k] = a_;  iW[k] = w_;
        tTotA[k] = __shfl(a_, 63, 64);
        tTotW[k] = __shfl(w_, 63, 64);
    }

    // Finish the cross-block exclusive prefix (loads long since landed).
    double offA, offW;
    {
#pragma unroll
        for (int off = 32; off > 0; off >>= 1) {
            vA += __shfl_down(vA, off, 64);
            vW += __shfl_down(vW, off, 64);
        }
        offA = __shfl(vA, 0, 64);
        offW = __shfl(vW, 0, 64);
    }

    // Combine + sOut staging.
    double accA = offA, accW = offW;   // running totals before current 64-tile
#pragma unroll
    for (int k = 0; k < 4; ++k) {
        const int tl = k * 64 + lane;
        const int t  = b * CHUNK + tl;
        const double runA = accA + iA[k];
        const double runW = accW + iW[k];
        const double vel = v0 + dt * runA;
        const double pos = p0 + dt * (double)(t + 1) * v0
                         + dt2 * (((double)t + 0.5) * runA - runW);
        sOut[tl * STATE + c]       = (float)pos;
        sOut[tl * STATE + NCH + c] = (float)vel;
        accA += tTotA[k];
        accW += tTotW[k];
    }
    __syncthreads();

    // Coalesced writeout of the 256x12 state chunk: 768 float4, 2/thread.
    const float4* so4 = (const float4*)sOut;
    out4[b * (CHUNK * STATE / 4) + tid]       = so4[tid];
    out4[b * (CHUNK * STATE / 4) + BLK + tid] = so4[BLK + tid];
}

extern "C" void kernel_launch(void* const* d_in, const int* in_sizes, int n_in,
                              void* d_out, int out_size, void* d_ws, size_t ws_size,
                              hipStream_t stream) {
    const float* x       = (const float*)d_in[0];   // 12 floats: pos(6), vel(6)
    const float* actions = (const float*)d_in[1];   // [65536, 6]
    float*       out     = (float*)d_out;           // states(786432) + actions(393216)
    double*      bsum    = (double*)d_ws;           // NB*NCH*2 doubles = 24 KiB

    hipLaunchKernelGGL(k_partial, dim3(NB), dim3(BLK), 0, stream,
                       (const float4*)actions, (float4*)(out + ACT_OFF), bsum);
    hipLaunchKernelGGL(k_final, dim3(NB), dim3(BLK), 0, stream,
                       (const float4*)actions, x, bsum, (float4*)out);
}